// Round 27
// baseline (85.410 us; speedup 1.0000x reference)
//
#include <hip/hip_runtime.h>
#include <hip/hip_bf16.h>

// Problem constants
#define HSZ 32
#define HP1 33
#define M3 35937            // 33^3 (flattened j,k,l)
#define TI_STRIDE 1149984   // 33^3 * 32 floats (stride of T over i)
#define TIB ((size_t)TI_STRIDE * 4)
#define NBLK 1124           // one wave per block, 32 m's per block
#define NT 64               // partial output tiles (contention 1124/64 ~ 18)
#define DEPTH 6             // ring slots (4KB each)
#define NHT 6144            // LDS float offset of staged nhT table
#define NHTG_FLOATS 4352    // staged floats (4224 real + zero pad)

// ws layout (bytes): nhTg @ 0 (17,408 B) ; tiles @ 32768 (262,144 B)
#define OFF_TILES 32768

typedef short bf16x8 __attribute__((ext_vector_type(8)));
typedef float f32x16 __attribute__((ext_vector_type(16)));

__device__ inline short f2bf(float f) {
  __hip_bfloat16 h = __float2bfloat16(f);  // RTNE; pairs into v_cvt_pk_bf16_f32
  return __builtin_bit_cast(short, h);
}

// Micro-prologue (r23 verbatim): 64 blocks zero tiles; block 64 builds nhTg.
__global__ __launch_bounds__(256) void k_pre(const float* __restrict__ nh,
                                             float* __restrict__ nhTg,
                                             float* __restrict__ tiles) {
  const int blk = (int)blockIdx.x;
  const int t = (int)threadIdx.x;
  if (blk < 64) {
    ((float4*)tiles)[blk * 256 + t] = make_float4(0.f, 0.f, 0.f, 0.f);
  } else {
    for (int x = t; x < NHTG_FLOATS; x += 256) {
      float v = 0.f;
      if (x < 4224) {
        const int d = x / 1056;
        const int rem = x - d * 1056;
        const int row = rem >> 5;
        const int b = rem & 31;
        v = (row < HSZ) ? nh[b * 128 + d * 32 + row] : 1.0f;
      }
      nhTg[x] = v;
    }
  }
}

// Main (r23 skeleton, ONE mechanism change): T rows travel via
// global_load_dwordx4 -> VGPR sets (regular vector return path, deep MSHRs)
// -> ds_write_b128 -> ds_read shuffle, instead of the LDS-DMA engine.
// Tests the hypothesis that the per-CU LDS-DMA queue (~11 ops) is the
// 4.75 TB/s throttle. Same counted-vmcnt schedule (steady 20, drain 16..0).
__global__ __launch_bounds__(64) void k_main(const float* __restrict__ T,
                                             const float* __restrict__ nhTg,
                                             float* __restrict__ tiles) {
  __shared__ float lds[DEPTH * 1024 + NHTG_FLOATS];  // 24KB ring + 17KB nhT
  const int blk = blockIdx.x;
  const int m0 = blk * 32;
  const int l = (int)threadIdx.x;  // 0..63
  const int bo = l & 31;           // A row (b) / B col (o)
  const int g = l >> 5;            // k-group: k = 8*g + e

  // Per-lane source byte offsets: op q covers row floats [q*256+4l, +4)
  const int mrel = l >> 3;
  size_t src[4];
#pragma unroll
  for (int q = 0; q < 4; ++q) {
    const bool valid = (m0 + 8 * q + mrel) < M3;
    src[q] = valid ? ((size_t)(m0 * 32 + q * 256 + l * 4) * 4) : 0;
  }
  const char* Tb = (const char*)T;
  const char* Ng = (const char*)nhTg;

  // (1) Stage nhT -> LDS: 17 DMA ops (tiny; engine queue irrelevant here).
#pragma unroll
  for (int q = 0; q < 17; ++q) {
    __builtin_amdgcn_global_load_lds(
        (const __attribute__((address_space(1))) void*)(Ng + q * 1024 + l * 16),
        (__attribute__((address_space(3))) void*)(&lds[NHT + q * 256]),
        16, 0, 0);
  }

  // VGPR staging sets: 6 rows x 4 float4 = 96 VGPRs (all indices constant
  // under full unroll -> registers).
  float4 vA[DEPTH][4];

#define ISSUE(row_, set_)                                                     \
  {                                                                           \
    _Pragma("unroll")                                                         \
    for (int q = 0; q < 4; ++q) {                                             \
      vA[set_][q] =                                                           \
          *(const float4*)(Tb + (size_t)(row_)*TIB + src[q]);                 \
    }                                                                         \
  }

  // (2) Fill the pipeline: 24 dwordx4 loads in flight behind the 17 DMA ops.
  ISSUE(0, 0) ISSUE(1, 1) ISSUE(2, 2) ISSUE(3, 3) ISSUE(4, 4) ISSUE(5, 5)

  // (3) Wait for nhT only (T loads stay in flight), then build df from LDS.
  asm volatile("s_waitcnt vmcnt(24)" ::: "memory");
  __builtin_amdgcn_sched_barrier(0);

  float df0[8], df1[8];
#pragma unroll
  for (int e = 0; e < 8; ++e) {
#pragma unroll
    for (int half = 0; half < 2; ++half) {
      const int m = m0 + 16 * half + 8 * g + e;
      const bool valid = m < M3;
      const int mc = valid ? m : (M3 - 1);
      const int j = mc / 1089;
      const int r = mc - j * 1089;
      const int kk = r / 33;
      const int ll = r - kk * 33;
      const float a1 = lds[NHT + 1056 + j * 32 + bo];
      const float a2 = lds[NHT + 2112 + kk * 32 + bo];
      const float a3 = lds[NHT + 3168 + ll * 32 + bo];
      const float v = valid ? (a1 * a2 * a3) : 0.0f;
      if (half == 0) df0[e] = v; else df1[e] = v;
    }
  }

  f32x16 acc = {};

#define STEP(i_, vm_, doIssue_)                                               \
  {                                                                           \
    asm volatile("s_waitcnt vmcnt(" #vm_ ")" ::: "memory");                   \
    __builtin_amdgcn_sched_barrier(0);                                        \
    _Pragma("unroll")                                                         \
    for (int q = 0; q < 4; ++q) {                                             \
      *(float4*)&lds[((i_) % DEPTH) * 1024 + q * 256 + 4 * l] =               \
          vA[(i_) % DEPTH][q];                                                \
    }                                                                         \
    asm volatile("s_waitcnt lgkmcnt(0)" ::: "memory");                        \
    __builtin_amdgcn_sched_barrier(0);                                        \
    float tv0[8], tv1[8];                                                     \
    const float a0 = lds[NHT + (i_)*32 + bo];                                 \
    _Pragma("unroll")                                                         \
    for (int e = 0; e < 8; ++e) {                                             \
      tv0[e] = lds[((i_) % DEPTH) * 1024 + (8 * g + e) * 32 + bo];            \
      tv1[e] = lds[((i_) % DEPTH) * 1024 + 512 + (8 * g + e) * 32 + bo];      \
    }                                                                         \
    bf16x8 af0, bf0, af1, bf1;                                                \
    _Pragma("unroll")                                                         \
    for (int e = 0; e < 8; ++e) {                                             \
      af0[e] = f2bf(a0 * df0[e]);                                             \
      bf0[e] = f2bf(tv0[e]);                                                  \
      af1[e] = f2bf(a0 * df1[e]);                                             \
      bf1[e] = f2bf(tv1[e]);                                                  \
    }                                                                         \
    acc = __builtin_amdgcn_mfma_f32_32x32x16_bf16(af0, bf0, acc, 0, 0, 0);    \
    acc = __builtin_amdgcn_mfma_f32_32x32x16_bf16(af1, bf1, acc, 0, 0, 0);    \
    if (doIssue_) { ISSUE((i_) + DEPTH, (i_) % DEPTH) }                       \
  }

  // 33 steps: steady vmcnt(20) while issuing (i<=26), then drain.
  STEP(0, 20, 1)  STEP(1, 20, 1)  STEP(2, 20, 1)  STEP(3, 20, 1)
  STEP(4, 20, 1)  STEP(5, 20, 1)  STEP(6, 20, 1)  STEP(7, 20, 1)
  STEP(8, 20, 1)  STEP(9, 20, 1)  STEP(10, 20, 1) STEP(11, 20, 1)
  STEP(12, 20, 1) STEP(13, 20, 1) STEP(14, 20, 1) STEP(15, 20, 1)
  STEP(16, 20, 1) STEP(17, 20, 1) STEP(18, 20, 1) STEP(19, 20, 1)
  STEP(20, 20, 1) STEP(21, 20, 1) STEP(22, 20, 1) STEP(23, 20, 1)
  STEP(24, 20, 1) STEP(25, 20, 1) STEP(26, 20, 1) STEP(27, 20, 0)
  STEP(28, 16, 0) STEP(29, 12, 0) STEP(30, 8, 0)  STEP(31, 4, 0)
  STEP(32, 0, 0)
#undef STEP
#undef ISSUE

  // Accumulate into one of NT partial tiles (r23 epilogue verbatim).
  // C/D layout (m74/m101): col=lane&31, row=(r&3)+8*(r>>2)+4*(lane>>5)
  float* tp = tiles + (size_t)(blk & (NT - 1)) * 1024;
#pragma unroll
  for (int r = 0; r < 16; ++r) {
    const int brow = (r & 3) + 8 * (r >> 2) + 4 * g;
    atomicAdd(tp + brow * 32 + bo, acc[r]);
  }
}

// Final reduce (r23 verbatim): out[idx] = sum over NT tiles.
__global__ __launch_bounds__(256) void k_red(const float* __restrict__ tiles,
                                             float* __restrict__ out) {
  const int idx = blockIdx.x * 256 + (int)threadIdx.x;
  float s = 0.f;
  for (int t = 0; t < NT; ++t) s += tiles[(size_t)t * 1024 + idx];
  out[idx] = s;
}

extern "C" void kernel_launch(void* const* d_in, const int* in_sizes, int n_in,
                              void* d_out, int out_size, void* d_ws, size_t ws_size,
                              hipStream_t stream) {
  const float* nh = (const float*)d_in[0];  // [32,4,32]
  const float* T  = (const float*)d_in[1];  // [33,33,33,33,32]
  float* out = (float*)d_out;               // [32,32] fp32
  char* ws = (char*)d_ws;
  float* nhTg  = (float*)ws;
  float* tiles = (float*)(ws + OFF_TILES);

  k_pre<<<65, 256, 0, stream>>>(nh, nhTg, tiles);
  k_main<<<NBLK, 64, 0, stream>>>(T, nhTg, tiles);
  k_red<<<4, 256, 0, stream>>>(tiles, out);
}

// Round 28
// 40.873 us; speedup vs baseline: 2.0897x; 2.0897x over previous
//
#include <hip/hip_runtime.h>
#include <hip/hip_bf16.h>

// Problem constants
#define HSZ 32
#define HP1 33
#define M3 35937            // 33^3 (flattened j,k,l)
#define TI_STRIDE 1149984   // 33^3 * 32 floats (stride of T over i)
#define TIB ((size_t)TI_STRIDE * 4)
#define NBLK 1124           // one wave per block, 32 m's per block
#define NT 64               // partial output tiles (contention 1124/64 ~ 18)
#define DEPTH 6             // ring slots (4KB each)
#define NHT 6144            // LDS float offset of staged nhT table
#define NHTG_FLOATS 4352    // staged floats (4224 real + zero pad)

// ws layout (bytes): nhTg @ 0 (17,408 B) ; tiles @ 32768 (262,144 B)
#define OFF_TILES 32768

typedef short bf16x8 __attribute__((ext_vector_type(8)));
typedef float f32x16 __attribute__((ext_vector_type(16)));

__device__ inline short f2bf(float f) {
  __hip_bfloat16 h = __float2bfloat16(f);  // RTNE; pairs into v_cvt_pk_bf16_f32
  return __builtin_bit_cast(short, h);
}

// Micro-prologue (r23 verbatim): 64 blocks zero tiles; block 64 builds nhTg.
__global__ __launch_bounds__(256) void k_pre(const float* __restrict__ nh,
                                             float* __restrict__ nhTg,
                                             float* __restrict__ tiles) {
  const int blk = (int)blockIdx.x;
  const int t = (int)threadIdx.x;
  if (blk < 64) {
    ((float4*)tiles)[blk * 256 + t] = make_float4(0.f, 0.f, 0.f, 0.f);
  } else {
    for (int x = t; x < NHTG_FLOATS; x += 256) {
      float v = 0.f;
      if (x < 4224) {
        const int d = x / 1056;
        const int rem = x - d * 1056;
        const int row = rem >> 5;
        const int b = rem & 31;
        v = (row < HSZ) ? nh[b * 128 + d * 32 + row] : 1.0f;
      }
      nhTg[x] = v;
    }
  }
}

// Main: r27's vector-path test, DE-CONFOUNDED: __launch_bounds__(64,1)
// (no artificial VGPR cap -> no scratch spill) and 24 NAMED float4 staging
// registers (compile-time-constant accesses only). T rows: global_load_
// dwordx4 -> named VGPRs -> ds_write_b128 -> ds_read shuffle. Same counted
// vmcnt schedule as r23 (steady 20, drain 16..0).
__global__ __launch_bounds__(64, 1) void k_main(const float* __restrict__ T,
                                                const float* __restrict__ nhTg,
                                                float* __restrict__ tiles) {
  __shared__ float lds[DEPTH * 1024 + NHTG_FLOATS];  // 24KB ring + 17KB nhT
  const int blk = blockIdx.x;
  const int m0 = blk * 32;
  const int l = (int)threadIdx.x;  // 0..63
  const int bo = l & 31;           // A row (b) / B col (o)
  const int g = l >> 5;            // k-group: k = 8*g + e

  // Per-lane source byte offsets: op q covers row floats [q*256+4l, +4)
  const int mrel = l >> 3;
  size_t src[4];
#pragma unroll
  for (int q = 0; q < 4; ++q) {
    const bool valid = (m0 + 8 * q + mrel) < M3;
    src[q] = valid ? ((size_t)(m0 * 32 + q * 256 + l * 4) * 4) : 0;
  }
  const char* Tb = (const char*)T;
  const char* Ng = (const char*)nhTg;

  // (1) Stage nhT -> LDS: 17 DMA ops (oldest in the vmcnt queue).
#pragma unroll
  for (int q = 0; q < 17; ++q) {
    __builtin_amdgcn_global_load_lds(
        (const __attribute__((address_space(1))) void*)(Ng + q * 1024 + l * 16),
        (__attribute__((address_space(3))) void*)(&lds[NHT + q * 256]),
        16, 0, 0);
  }

  // 24 named staging registers (6 sets x 4 float4 = 96 VGPRs, all static).
  float4 sA0, sA1, sA2, sA3, sB0, sB1, sB2, sB3, sC0, sC1, sC2, sC3;
  float4 sD0, sD1, sD2, sD3, sE0, sE1, sE2, sE3, sF0, sF1, sF2, sF3;

#define ISSUE(row_, Q0, Q1, Q2, Q3)                      \
  {                                                      \
    const char* bp_ = Tb + (size_t)(row_)*TIB;           \
    Q0 = *(const float4*)(bp_ + src[0]);                 \
    Q1 = *(const float4*)(bp_ + src[1]);                 \
    Q2 = *(const float4*)(bp_ + src[2]);                 \
    Q3 = *(const float4*)(bp_ + src[3]);                 \
  }

  // (2) Fill the pipeline: 24 dwordx4 loads in flight behind the 17 DMA ops.
  ISSUE(0, sA0, sA1, sA2, sA3) ISSUE(1, sB0, sB1, sB2, sB3)
  ISSUE(2, sC0, sC1, sC2, sC3) ISSUE(3, sD0, sD1, sD2, sD3)
  ISSUE(4, sE0, sE1, sE2, sE3) ISSUE(5, sF0, sF1, sF2, sF3)

  // (3) Wait for nhT only (T loads stay in flight), then build df from LDS.
  asm volatile("s_waitcnt vmcnt(24)" ::: "memory");
  __builtin_amdgcn_sched_barrier(0);

  float df0[8], df1[8];
#pragma unroll
  for (int e = 0; e < 8; ++e) {
#pragma unroll
    for (int half = 0; half < 2; ++half) {
      const int m = m0 + 16 * half + 8 * g + e;
      const bool valid = m < M3;
      const int mc = valid ? m : (M3 - 1);
      const int j = mc / 1089;
      const int r = mc - j * 1089;
      const int kk = r / 33;
      const int ll = r - kk * 33;
      const float a1 = lds[NHT + 1056 + j * 32 + bo];
      const float a2 = lds[NHT + 2112 + kk * 32 + bo];
      const float a3 = lds[NHT + 3168 + ll * 32 + bo];
      const float v = valid ? (a1 * a2 * a3) : 0.0f;
      if (half == 0) df0[e] = v; else df1[e] = v;
    }
  }

  f32x16 acc = {};

#define STEP(i_, Q0, Q1, Q2, Q3, vm_, doIssue_)                               \
  {                                                                           \
    asm volatile("s_waitcnt vmcnt(" #vm_ ")" ::: "memory");                   \
    __builtin_amdgcn_sched_barrier(0);                                        \
    *(float4*)&lds[((i_) % DEPTH) * 1024 + 0 * 256 + 4 * l] = Q0;             \
    *(float4*)&lds[((i_) % DEPTH) * 1024 + 1 * 256 + 4 * l] = Q1;             \
    *(float4*)&lds[((i_) % DEPTH) * 1024 + 2 * 256 + 4 * l] = Q2;             \
    *(float4*)&lds[((i_) % DEPTH) * 1024 + 3 * 256 + 4 * l] = Q3;             \
    asm volatile("s_waitcnt lgkmcnt(0)" ::: "memory");                        \
    __builtin_amdgcn_sched_barrier(0);                                        \
    float tv0[8], tv1[8];                                                     \
    const float a0 = lds[NHT + (i_)*32 + bo];                                 \
    _Pragma("unroll")                                                         \
    for (int e = 0; e < 8; ++e) {                                             \
      tv0[e] = lds[((i_) % DEPTH) * 1024 + (8 * g + e) * 32 + bo];            \
      tv1[e] = lds[((i_) % DEPTH) * 1024 + 512 + (8 * g + e) * 32 + bo];      \
    }                                                                         \
    bf16x8 af0, bf0, af1, bf1;                                                \
    _Pragma("unroll")                                                         \
    for (int e = 0; e < 8; ++e) {                                             \
      af0[e] = f2bf(a0 * df0[e]);                                             \
      bf0[e] = f2bf(tv0[e]);                                                  \
      af1[e] = f2bf(a0 * df1[e]);                                             \
      bf1[e] = f2bf(tv1[e]);                                                  \
    }                                                                         \
    acc = __builtin_amdgcn_mfma_f32_32x32x16_bf16(af0, bf0, acc, 0, 0, 0);    \
    acc = __builtin_amdgcn_mfma_f32_32x32x16_bf16(af1, bf1, acc, 0, 0, 0);    \
    if (doIssue_) { ISSUE((i_) + DEPTH, Q0, Q1, Q2, Q3) }                     \
  }

  // 33 steps: steady vmcnt(20) while issuing (i<=26), then drain.
  STEP(0,  sA0, sA1, sA2, sA3, 20, 1) STEP(1,  sB0, sB1, sB2, sB3, 20, 1)
  STEP(2,  sC0, sC1, sC2, sC3, 20, 1) STEP(3,  sD0, sD1, sD2, sD3, 20, 1)
  STEP(4,  sE0, sE1, sE2, sE3, 20, 1) STEP(5,  sF0, sF1, sF2, sF3, 20, 1)
  STEP(6,  sA0, sA1, sA2, sA3, 20, 1) STEP(7,  sB0, sB1, sB2, sB3, 20, 1)
  STEP(8,  sC0, sC1, sC2, sC3, 20, 1) STEP(9,  sD0, sD1, sD2, sD3, 20, 1)
  STEP(10, sE0, sE1, sE2, sE3, 20, 1) STEP(11, sF0, sF1, sF2, sF3, 20, 1)
  STEP(12, sA0, sA1, sA2, sA3, 20, 1) STEP(13, sB0, sB1, sB2, sB3, 20, 1)
  STEP(14, sC0, sC1, sC2, sC3, 20, 1) STEP(15, sD0, sD1, sD2, sD3, 20, 1)
  STEP(16, sE0, sE1, sE2, sE3, 20, 1) STEP(17, sF0, sF1, sF2, sF3, 20, 1)
  STEP(18, sA0, sA1, sA2, sA3, 20, 1) STEP(19, sB0, sB1, sB2, sB3, 20, 1)
  STEP(20, sC0, sC1, sC2, sC3, 20, 1) STEP(21, sD0, sD1, sD2, sD3, 20, 1)
  STEP(22, sE0, sE1, sE2, sE3, 20, 1) STEP(23, sF0, sF1, sF2, sF3, 20, 1)
  STEP(24, sA0, sA1, sA2, sA3, 20, 1) STEP(25, sB0, sB1, sB2, sB3, 20, 1)
  STEP(26, sC0, sC1, sC2, sC3, 20, 1) STEP(27, sD0, sD1, sD2, sD3, 20, 0)
  STEP(28, sE0, sE1, sE2, sE3, 16, 0) STEP(29, sF0, sF1, sF2, sF3, 12, 0)
  STEP(30, sA0, sA1, sA2, sA3, 8, 0)  STEP(31, sB0, sB1, sB2, sB3, 4, 0)
  STEP(32, sC0, sC1, sC2, sC3, 0, 0)
#undef STEP
#undef ISSUE

  // Accumulate into one of NT partial tiles (r23 epilogue verbatim).
  // C/D layout (m74/m101): col=lane&31, row=(r&3)+8*(r>>2)+4*(lane>>5)
  float* tp = tiles + (size_t)(blk & (NT - 1)) * 1024;
#pragma unroll
  for (int r = 0; r < 16; ++r) {
    const int brow = (r & 3) + 8 * (r >> 2) + 4 * g;
    atomicAdd(tp + brow * 32 + bo, acc[r]);
  }
}

// Final reduce (r23 verbatim): out[idx] = sum over NT tiles.
__global__ __launch_bounds__(256) void k_red(const float* __restrict__ tiles,
                                             float* __restrict__ out) {
  const int idx = blockIdx.x * 256 + (int)threadIdx.x;
  float s = 0.f;
  for (int t = 0; t < NT; ++t) s += tiles[(size_t)t * 1024 + idx];
  out[idx] = s;
}

extern "C" void kernel_launch(void* const* d_in, const int* in_sizes, int n_in,
                              void* d_out, int out_size, void* d_ws, size_t ws_size,
                              hipStream_t stream) {
  const float* nh = (const float*)d_in[0];  // [32,4,32]
  const float* T  = (const float*)d_in[1];  // [33,33,33,33,32]
  float* out = (float*)d_out;               // [32,32] fp32
  char* ws = (char*)d_ws;
  float* nhTg  = (float*)ws;
  float* tiles = (float*)(ws + OFF_TILES);

  k_pre<<<65, 256, 0, stream>>>(nh, nhTg, tiles);
  k_main<<<NBLK, 64, 0, stream>>>(T, nhTg, tiles);
  k_red<<<4, 256, 0, stream>>>(tiles, out);
}

// Round 29
// 39.565 us; speedup vs baseline: 2.1587x; 1.0330x over previous
//
#include <hip/hip_runtime.h>
#include <hip/hip_bf16.h>

// ============================================================================
// Full_67568425501232: out[b][o] = sum_{i,m} a0[b,i]*(a1*a2*a3)[b,m]*T[i][m][o]
// (degree-4 multilinear contraction, T = 33^4 x 32 fp32 = 152 MB, read once)
//
// Final structure (session best, 39.19 us; 4.0x over first passing kernel):
//  - k_pre (65 blocks): zero 64 partial tiles; build 17KB transposed nh table.
//  - k_main (1124 one-wave blocks, 32 m's each): T streams through a 6-slot
//    4KB LDS ring via global_load_lds with counted vmcnt (steady 20, never
//    drained mid-loop); nh table staged to LDS ahead of the ring; A-fragment
//    built in-wave under ring flight; bf16 cvt via v_cvt_pk; 2 MFMAs/step
//    (v_mfma_f32_32x32x16_bf16); epilogue = 16 fire-and-forget atomicAdds
//    into 64 shared tiles (4096 lines, ~18 contenders/address).
//  - k_red (4 blocks): fold 64 tiles -> d_out.
// ============================================================================
#define HSZ 32
#define HP1 33
#define M3 35937            // 33^3 (flattened j,k,l)
#define TI_STRIDE 1149984   // 33^3 * 32 floats (stride of T over i)
#define TIB ((size_t)TI_STRIDE * 4)
#define NBLK 1124           // one wave per block, 32 m's per block
#define NT 64               // partial output tiles (contention 1124/64 ~ 18)
#define DEPTH 6             // LDS ring slots (4KB each)
#define NHT 6144            // LDS float offset of staged nhT table
#define NHTG_FLOATS 4352    // staged floats (4224 real + zero pad)

// ws layout (bytes): nhTg @ 0 (17,408 B) ; tiles @ 32768 (262,144 B)
#define OFF_TILES 32768

typedef short bf16x8 __attribute__((ext_vector_type(8)));
typedef float f32x16 __attribute__((ext_vector_type(16)));

__device__ inline short f2bf(float f) {
  __hip_bfloat16 h = __float2bfloat16(f);  // RTNE; pairs into v_cvt_pk_bf16_f32
  return __builtin_bit_cast(short, h);
}

// Micro-prologue: 64 blocks zero tiles; block 64 builds transposed table
// nhTg[d*1056 + x*32 + b] (x=32 row = 1.0 bias; floats 4224.. zero pad).
__global__ __launch_bounds__(256) void k_pre(const float* __restrict__ nh,
                                             float* __restrict__ nhTg,
                                             float* __restrict__ tiles) {
  const int blk = (int)blockIdx.x;
  const int t = (int)threadIdx.x;
  if (blk < 64) {
    ((float4*)tiles)[blk * 256 + t] = make_float4(0.f, 0.f, 0.f, 0.f);
  } else {
    for (int x = t; x < NHTG_FLOATS; x += 256) {
      float v = 0.f;
      if (x < 4224) {
        const int d = x / 1056;
        const int rem = x - d * 1056;
        const int row = rem >> 5;
        const int b = rem & 31;
        v = (row < HSZ) ? nh[b * 128 + d * 32 + row] : 1.0f;
      }
      nhTg[x] = v;
    }
  }
}

// Main: one wave per block; block owns 32 m's. 6-slot x 4KB LDS DMA ring,
// counted vmcnt(20) steady state; nhT staged to LDS via 17 DMA ops issued
// before the ring; df built in-wave (hidden under ring fill); lgkmcnt(0) +
// DMA reissue placed AFTER the MFMAs (LDS latency hides under compute).
__global__ __launch_bounds__(64) void k_main(const float* __restrict__ T,
                                             const float* __restrict__ nhTg,
                                             float* __restrict__ tiles) {
  __shared__ float lds[DEPTH * 1024 + NHTG_FLOATS];  // 24KB ring + 17KB nhT
  const int blk = blockIdx.x;
  const int m0 = blk * 32;
  const int l = (int)threadIdx.x;  // 0..63
  const int bo = l & 31;           // A row (b) / B col (o)
  const int g = l >> 5;            // k-group: k = 8*g + e

  // Per-lane DMA source byte offsets: op q covers row floats [q*256+4l, +4)
  const int mrel = l >> 3;
  size_t src[4];
#pragma unroll
  for (int q = 0; q < 4; ++q) {
    const bool valid = (m0 + 8 * q + mrel) < M3;
    src[q] = valid ? ((size_t)(m0 * 32 + q * 256 + l * 4) * 4) : 0;
  }
  const char* Tb = (const char*)T;
  const char* Ng = (const char*)nhTg;

  // (1) Stage nhT -> LDS: 17 DMA ops (oldest in the vmcnt queue).
#pragma unroll
  for (int q = 0; q < 17; ++q) {
    __builtin_amdgcn_global_load_lds(
        (const __attribute__((address_space(1))) void*)(Ng + q * 1024 + l * 16),
        (__attribute__((address_space(3))) void*)(&lds[NHT + q * 256]),
        16, 0, 0);
  }

#define ISSUE(row_, slot_)                                                    \
  {                                                                           \
    _Pragma("unroll")                                                         \
    for (int q = 0; q < 4; ++q) {                                             \
      __builtin_amdgcn_global_load_lds(                                       \
          (const __attribute__((address_space(1))) void*)(                    \
              Tb + (size_t)(row_)*TIB + src[q]),                              \
          (__attribute__((address_space(3))) void*)(                          \
              &lds[(slot_)*1024 + q * 256]),                                  \
          16, 0, 0);                                                          \
    }                                                                         \
  }

  // (2) Fill the ring: 24 DMA ops in flight behind the 17 nhT ops.
  ISSUE(0, 0) ISSUE(1, 1) ISSUE(2, 2) ISSUE(3, 3) ISSUE(4, 4) ISSUE(5, 5)

  // (3) Wait for nhT only (ring stays in flight), then build df from LDS.
  asm volatile("s_waitcnt vmcnt(24)" ::: "memory");
  __builtin_amdgcn_sched_barrier(0);

  float df0[8], df1[8];
#pragma unroll
  for (int e = 0; e < 8; ++e) {
#pragma unroll
    for (int half = 0; half < 2; ++half) {
      const int m = m0 + 16 * half + 8 * g + e;
      const bool valid = m < M3;
      const int mc = valid ? m : (M3 - 1);
      const int j = mc / 1089;
      const int r = mc - j * 1089;
      const int kk = r / 33;
      const int ll = r - kk * 33;
      const float a1 = lds[NHT + 1056 + j * 32 + bo];
      const float a2 = lds[NHT + 2112 + kk * 32 + bo];
      const float a3 = lds[NHT + 3168 + ll * 32 + bo];
      const float v = valid ? (a1 * a2 * a3) : 0.0f;
      if (half == 0) df0[e] = v; else df1[e] = v;
    }
  }

  f32x16 acc = {};

#define STEP(i_, vm_, doIssue_)                                               \
  {                                                                           \
    asm volatile("s_waitcnt vmcnt(" #vm_ ")" ::: "memory");                   \
    __builtin_amdgcn_sched_barrier(0);                                        \
    float tv0[8], tv1[8];                                                     \
    const float a0 = lds[NHT + (i_)*32 + bo];                                 \
    _Pragma("unroll")                                                         \
    for (int e = 0; e < 8; ++e) {                                             \
      tv0[e] = lds[((i_) % DEPTH) * 1024 + (8 * g + e) * 32 + bo];            \
      tv1[e] = lds[((i_) % DEPTH) * 1024 + 512 + (8 * g + e) * 32 + bo];      \
    }                                                                         \
    bf16x8 af0, bf0, af1, bf1;                                                \
    _Pragma("unroll")                                                         \
    for (int e = 0; e < 8; ++e) {                                             \
      af0[e] = f2bf(a0 * df0[e]);                                             \
      bf0[e] = f2bf(tv0[e]);                                                  \
      af1[e] = f2bf(a0 * df1[e]);                                             \
      bf1[e] = f2bf(tv1[e]);                                                  \
    }                                                                         \
    acc = __builtin_amdgcn_mfma_f32_32x32x16_bf16(af0, bf0, acc, 0, 0, 0);    \
    acc = __builtin_amdgcn_mfma_f32_32x32x16_bf16(af1, bf1, acc, 0, 0, 0);    \
    if (doIssue_) {                                                           \
      asm volatile("s_waitcnt lgkmcnt(0)" ::: "memory");                      \
      __builtin_amdgcn_sched_barrier(0);                                      \
      ISSUE((i_) + DEPTH, (i_) % DEPTH)                                       \
    }                                                                         \
  }

  // 33 steps: steady vmcnt(20) while issuing (i<=26), then drain.
  STEP(0, 20, 1)  STEP(1, 20, 1)  STEP(2, 20, 1)  STEP(3, 20, 1)
  STEP(4, 20, 1)  STEP(5, 20, 1)  STEP(6, 20, 1)  STEP(7, 20, 1)
  STEP(8, 20, 1)  STEP(9, 20, 1)  STEP(10, 20, 1) STEP(11, 20, 1)
  STEP(12, 20, 1) STEP(13, 20, 1) STEP(14, 20, 1) STEP(15, 20, 1)
  STEP(16, 20, 1) STEP(17, 20, 1) STEP(18, 20, 1) STEP(19, 20, 1)
  STEP(20, 20, 1) STEP(21, 20, 1) STEP(22, 20, 1) STEP(23, 20, 1)
  STEP(24, 20, 1) STEP(25, 20, 1) STEP(26, 20, 1) STEP(27, 20, 0)
  STEP(28, 16, 0) STEP(29, 12, 0) STEP(30, 8, 0)  STEP(31, 4, 0)
  STEP(32, 0, 0)
#undef STEP
#undef ISSUE

  // Accumulate into one of NT partial tiles.
  // C/D layout (m74/m101): col=lane&31, row=(r&3)+8*(r>>2)+4*(lane>>5)
  float* tp = tiles + (size_t)(blk & (NT - 1)) * 1024;
#pragma unroll
  for (int r = 0; r < 16; ++r) {
    const int brow = (r & 3) + 8 * (r >> 2) + 4 * g;
    atomicAdd(tp + brow * 32 + bo, acc[r]);
  }
}

// Final reduce: out[idx] = sum over NT tiles.
__global__ __launch_bounds__(256) void k_red(const float* __restrict__ tiles,
                                             float* __restrict__ out) {
  const int idx = blockIdx.x * 256 + (int)threadIdx.x;
  float s = 0.f;
  for (int t = 0; t < NT; ++t) s += tiles[(size_t)t * 1024 + idx];
  out[idx] = s;
}

extern "C" void kernel_launch(void* const* d_in, const int* in_sizes, int n_in,
                              void* d_out, int out_size, void* d_ws, size_t ws_size,
                              hipStream_t stream) {
  const float* nh = (const float*)d_in[0];  // [32,4,32]
  const float* T  = (const float*)d_in[1];  // [33,33,33,33,32]
  float* out = (float*)d_out;               // [32,32] fp32
  char* ws = (char*)d_ws;
  float* nhTg  = (float*)ws;
  float* tiles = (float*)(ws + OFF_TILES);

  k_pre<<<65, 256, 0, stream>>>(nh, nhTg, tiles);
  k_main<<<NBLK, 64, 0, stream>>>(T, nhTg, tiles);
  k_red<<<4, 256, 0, stream>>>(tiles, out);
}